// Round 10
// baseline (185.791 us; speedup 1.0000x reference)
//
#include <hip/hip_runtime.h>
#include <hip/hip_bf16.h>
#include <cstddef>
#include <cstdint>

// B=2, S=2048, D=1024, H=16, KVH=4, hd=64. window from d_in[9].

typedef short v8s __attribute__((ext_vector_type(8)));
typedef float v4f __attribute__((ext_vector_type(4)));

// Exact RNE fp32->bf16 for FINITE values (no NaN path): 3 VALU ops.
__device__ __forceinline__ ushort b1(float a) {
  uint u = __float_as_uint(a);
  return (ushort)((u + 0x7FFFu + ((u >> 16) & 1u)) >> 16);
}
// Packed pair (lo, hi) -> one uint.
__device__ __forceinline__ uint bpack(float lo, float hi) {
  uint ul = __float_as_uint(lo), uh = __float_as_uint(hi);
  ul = (ul + 0x7FFFu + ((ul >> 16) & 1u)) >> 16;
  uh = (uh + 0x7FFFu + ((uh >> 16) & 1u)) & 0xFFFF0000u;
  return ul | uh;
}

// CK-style async global->LDS 16B/lane copy (wave-uniform LDS base + lane*16).
__device__ __forceinline__ void async16(const ushort* g, ushort* l) {
  __builtin_amdgcn_global_load_lds(
      (__attribute__((address_space(1))) void*)(uintptr_t)(const void*)g,
      (__attribute__((address_space(3))) void*)(uintptr_t)(void*)l, 16, 0, 0);
}

// ---------------- merged prep: x-cvt+gates | cs pack | 4 weight transposes --
// blocks 0..4095: x->bf16 + gates; 4096..4351: cs pack; 4352..6911: transposes.
__global__ __launch_bounds__(256) void prep_all(
    const float* __restrict__ x, ushort* __restrict__ xb,
    const float* __restrict__ Wg, float* __restrict__ gates,
    const float* __restrict__ cosp, const float* __restrict__ sinp,
    float2* __restrict__ cs,
    const float* __restrict__ Wq, const float* __restrict__ Wk,
    const float* __restrict__ Wv, const float* __restrict__ Wo,
    ushort* __restrict__ Wqt, ushort* __restrict__ Wkt,
    ushort* __restrict__ Wvt, ushort* __restrict__ Wot)
{
  const int bx = blockIdx.x, t = threadIdx.x;
  if (bx < 4096) {
    const float* row = x + (size_t)bx * 1024;
    float4 v = *(const float4*)(row + t * 4);
    ushort4 o;
    o.x = b1(v.x); o.y = b1(v.y); o.z = b1(v.z); o.w = b1(v.w);
    *(ushort4*)(xb + (size_t)bx * 1024 + t * 4) = o;
    if (t < 4) {
      float g = 0.f;
#pragma unroll
      for (int i = 0; i < 12; ++i) g += row[i] * Wg[i * 4 + t];
      gates[bx * 4 + t] = 3.0f / (1.0f + __expf(-g));
    }
    return;
  }
  if (bx < 4352) {
    const int i = (bx - 4096) * 256 + t;   // 65536 total
    cs[i] = make_float2(cosp[i], sinp[i]);
    return;
  }
  // transpose sections
  __shared__ ushort tile[32][33];
  int u = bx - 4352;
  const float* W; ushort* Wt; int N, xx, yy;
  if (u < 1024)      { W = Wq; Wt = Wqt; N = 1024; xx = u & 31; yy = u >> 5; }
  else if (u < 2048) { u -= 1024; W = Wo; Wt = Wot; N = 1024; xx = u & 31; yy = u >> 5; }
  else if (u < 2304) { u -= 2048; W = Wk; Wt = Wkt; N = 256;  xx = u & 7;  yy = u >> 3; }
  else               { u -= 2304; W = Wv; Wt = Wvt; N = 256;  xx = u & 7;  yy = u >> 3; }
  const int n0 = xx * 32, k0 = yy * 32;
  const int tx = t & 31, ty = t >> 5;
#pragma unroll
  for (int i = 0; i < 4; ++i) {
    const int k = ty + i * 8;
    tile[k][tx] = b1(W[(size_t)(k0 + k) * N + n0 + tx]);
  }
  __syncthreads();
#pragma unroll
  for (int i = 0; i < 4; ++i) {
    const int n = ty + i * 8;
    Wt[(size_t)(n0 + n) * 1024 + k0 + tx] = tile[tx][n];
  }
}

// ---------------- GEMM mainloop: 2-phase dbuf, 64x128, BK=64, T2 swizzle ---
//   store: lane loads global col ((lane&7)^(lane>>3))*8 -> linear dest
//   read : col = (ks*32+quad*8) ^ ((row&7)*8), row&7 == l16&7
__device__ __forceinline__ void gemm_mainloop(
    const ushort* __restrict__ A, const ushort* __restrict__ Bt,
    int K, int m0, int n0, ushort (*As)[64], ushort (*Bs)[64],
    v4f acc[2][4])
{
  const int t = threadIdx.x;
  const int lane = t & 63, wave = t >> 6;
  const int wr = wave >> 1, wc = wave & 1;
  const int quad = lane >> 4, l16 = lane & 15;
  const int l8 = lane >> 3;
  const int c8s = ((lane & 7) ^ l8) * 8;   // pre-swizzled global column
  const int sc = (l16 & 7) * 8;            // read-side XOR term

  const ushort* ap[2];
  ushort* al[2];
#pragma unroll
  for (int i = 0; i < 2; ++i) {
    const int row = wave * 8 + i * 32 + l8;   // row base multiple of 8
    ap[i] = A + (size_t)(m0 + row) * K + c8s;
    al[i] = &As[wave * 8 + i * 32][0];   // wave-uniform; HW adds lane*16B
  }
  const ushort* bp[4];
  ushort* bl[4];
#pragma unroll
  for (int i = 0; i < 4; ++i) {
    const int row = (wave * 4 + i) * 8 + l8;  // row base multiple of 8
    bp[i] = Bt + (size_t)(n0 + row) * K + c8s;
    bl[i] = &Bs[(wave * 4 + i) * 8][0];
  }

  auto stage = [&](int buf, int k0) {
#pragma unroll
    for (int i = 0; i < 2; ++i) async16(ap[i] + k0, al[i] + buf * (64 * 64));
#pragma unroll
    for (int i = 0; i < 4; ++i) async16(bp[i] + k0, bl[i] + buf * (128 * 64));
  };
  auto compute = [&](int buf) {
#pragma unroll
    for (int ks = 0; ks < 2; ++ks) {
      const int col = (ks * 32 + quad * 8) ^ sc;
      v8s af[2], bf[4];
#pragma unroll
      for (int i = 0; i < 2; ++i)
        af[i] = *(const v8s*)&As[buf * 64 + wr * 32 + i * 16 + l16][col];
#pragma unroll
      for (int i = 0; i < 4; ++i)
        bf[i] = *(const v8s*)&Bs[buf * 128 + wc * 64 + i * 16 + l16][col];
#pragma unroll
      for (int mt = 0; mt < 2; ++mt)
#pragma unroll
        for (int nt = 0; nt < 4; ++nt)
          acc[mt][nt] = __builtin_amdgcn_mfma_f32_16x16x32_bf16(
              af[mt], bf[nt], acc[mt][nt], 0, 0, 0);
    }
  };

  stage(0, 0);
  __syncthreads();
  int buf = 0;
  for (int k0 = 64; k0 < K; k0 += 64) {
    stage(buf ^ 1, k0);   // next tile in flight during compute
    compute(buf);
    __syncthreads();      // implicit vmcnt(0): prefetch done; buf reusable
    buf ^= 1;
  }
  compute(buf);           // last tile (no prefetch)
}

// ---------------- GEMM mainloop: 2-phase dbuf, 32x128 (gemm_wo), swizzled --
__device__ __forceinline__ void gemm_mainloop32(
    const ushort* __restrict__ A, const ushort* __restrict__ Bt,
    int K, int m0, int n0, ushort (*As)[64], ushort (*Bs)[64],
    v4f acc[4])
{
  const int t = threadIdx.x;
  const int lane = t & 63, wave = t >> 6;
  const int wr = wave >> 1, wc = wave & 1;
  const int quad = lane >> 4, l16 = lane & 15;
  const int l8 = lane >> 3;
  const int c8s = ((lane & 7) ^ l8) * 8;
  const int sc = (l16 & 7) * 8;

  const ushort* ap = A + (size_t)(m0 + wave * 8 + l8) * K + c8s;
  ushort* al = &As[wave * 8][0];
  const ushort* bp[4];
  ushort* bl[4];
#pragma unroll
  for (int i = 0; i < 4; ++i) {
    const int row = (wave * 4 + i) * 8 + l8;
    bp[i] = Bt + (size_t)(n0 + row) * K + c8s;
    bl[i] = &Bs[(wave * 4 + i) * 8][0];
  }

  auto stage = [&](int buf, int k0) {
    async16(ap + k0, al + buf * (32 * 64));
#pragma unroll
    for (int i = 0; i < 4; ++i) async16(bp[i] + k0, bl[i] + buf * (128 * 64));
  };
  auto compute = [&](int buf) {
#pragma unroll
    for (int ks = 0; ks < 2; ++ks) {
      const int col = (ks * 32 + quad * 8) ^ sc;
      v8s af = *(const v8s*)&As[buf * 32 + wr * 16 + l16][col];
      v8s bf[4];
#pragma unroll
      for (int i = 0; i < 4; ++i)
        bf[i] = *(const v8s*)&Bs[buf * 128 + wc * 64 + i * 16 + l16][col];
#pragma unroll
      for (int nt = 0; nt < 4; ++nt)
        acc[nt] = __builtin_amdgcn_mfma_f32_16x16x32_bf16(af, bf[nt], acc[nt], 0, 0, 0);
    }
  };

  stage(0, 0);
  __syncthreads();
  int buf = 0;
  for (int k0 = 64; k0 < K; k0 += 64) {
    stage(buf ^ 1, k0);
    compute(buf);
    __syncthreads();
    buf ^= 1;
  }
  compute(buf);
}

// ---------------- QKV GEMM with fused rope/rmsnorm/gate epilogue -----------
// XCD swizzle (T1): 768 blocks, 96/XCD.
__global__ __launch_bounds__(256) void gemm_qkv_fused(
    const ushort* __restrict__ A, const ushort* __restrict__ Bt,
    const float2* __restrict__ cs, const float* __restrict__ gates,
    const float* __restrict__ ve,
    ushort* __restrict__ qb, ushort* __restrict__ kb, ushort* __restrict__ vb)
{
  __shared__ ushort As[128][64];   // 2 x 64 rows (dbuf)
  __shared__ ushort Bs[256][64];   // 2 x 128 rows (dbuf)
  const int lin = blockIdx.y * 64 + blockIdx.x;        // [0,768)
  const int swz = (lin & 7) * 96 + (lin >> 3);         // bijective
  const int x8 = swz / 96, local = swz % 96;
  const int bxx = x8 * 8 + (local & 7), sec = local >> 3;
  const int m0 = bxx * 64, n0 = sec * 128;
  const int lane = threadIdx.x & 63, wave = threadIdx.x >> 6;
  const int wr = wave >> 1, wc = wave & 1;
  const int quad = lane >> 4, l16 = lane & 15;

  v4f acc[2][4];
#pragma unroll
  for (int i = 0; i < 2; ++i)
#pragma unroll
    for (int j = 0; j < 4; ++j) acc[i][j] = (v4f){0.f, 0.f, 0.f, 0.f};

  gemm_mainloop(A, Bt, 1024, m0, n0, As, Bs, acc);

  const int head_col = n0 + wc * 64;

  if (sec < 10) {
    const bool isQ = (sec < 8);
    const int h = (head_col - (isQ ? 0 : 1024)) >> 6;
    ushort* dst = isQ ? qb : kb;
    const int ld = isQ ? 1024 : 256;
#pragma unroll
    for (int mt = 0; mt < 2; ++mt)
#pragma unroll
      for (int r = 0; r < 4; ++r) {
        const int row = m0 + wr * 32 + mt * 16 + quad * 4 + r;
        const int s = row & 2047;
        const float2 cs0 = cs[s * 32 + l16];
        const float2 cs1 = cs[s * 32 + 16 + l16];
        const float x10 = acc[mt][0][r], x11 = acc[mt][1][r];
        const float x20 = acc[mt][2][r], x21 = acc[mt][3][r];
        float ss = x10 * x10 + x11 * x11 + x20 * x20 + x21 * x21;
        ss += __shfl_xor(ss, 1);
        ss += __shfl_xor(ss, 2);
        ss += __shfl_xor(ss, 4);
        ss += __shfl_xor(ss, 8);
        const float rs = rsqrtf(ss * (1.0f / 64.0f) + 1e-6f) * 1.2f;
        ushort* dp = dst + (size_t)row * ld + h * 64 + l16;
        dp[0]  = b1((x10 * cs0.x + x20 * cs0.y) * rs);
        dp[16] = b1((x11 * cs1.x + x21 * cs1.y) * rs);
        dp[32] = b1((-x10 * cs0.y + x20 * cs0.x) * rs);
        dp[48] = b1((-x11 * cs1.y + x21 * cs1.x) * rs);
      }
  } else {
    const int kvh = (head_col - 1280) >> 6;
#pragma unroll
    for (int mt = 0; mt < 2; ++mt)
#pragma unroll
      for (int r = 0; r < 4; ++r) {
        const int row = m0 + wr * 32 + mt * 16 + quad * 4 + r;
        const float gate = gates[row * 4 + kvh];
        const float* vep = ve + (size_t)row * 256 + kvh * 64 + l16;
        ushort* dp = vb + (size_t)row * 256 + kvh * 64 + l16;
#pragma unroll
        for (int nt = 0; nt < 4; ++nt)
          dp[nt * 16] = b1(acc[mt][nt][r] + gate * vep[nt * 16]);
      }
  }
}

// ---------------- Wo GEMM: 32x128 tile, plain fp32 epilogue ----------------
// XCD swizzle: 1024 blocks, 128/XCD.
__global__ __launch_bounds__(256) void gemm_wo(
    const ushort* __restrict__ A, const ushort* __restrict__ Bt,
    float* __restrict__ C)
{
  __shared__ ushort As[64][64];    // 2 x 32 rows (dbuf)
  __shared__ ushort Bs[256][64];   // 2 x 128 rows (dbuf)
  const int lin = blockIdx.y * 128 + blockIdx.x;       // [0,1024)
  const int swz = (lin & 7) * 128 + (lin >> 3);        // bijective
  const int x8 = swz >> 7, local = swz & 127;
  const int bxx = x8 * 16 + (local & 15), byy = local >> 4;
  const int m0 = bxx * 32, n0 = byy * 128;
  const int lane = threadIdx.x & 63, wave = threadIdx.x >> 6;
  const int wr = wave >> 1, wc = wave & 1;
  const int quad = lane >> 4, l16 = lane & 15;

  v4f acc[4];
#pragma unroll
  for (int j = 0; j < 4; ++j) acc[j] = (v4f){0.f, 0.f, 0.f, 0.f};

  gemm_mainloop32(A, Bt, 1024, m0, n0, As, Bs, acc);

#pragma unroll
  for (int r = 0; r < 4; ++r) {
    float* cp = C + (size_t)(m0 + wr * 16 + quad * 4 + r) * 1024
                  + n0 + wc * 64 + l16;
#pragma unroll
    for (int nt = 0; nt < 4; ++nt) cp[nt * 16] = acc[nt][r];
  }
}

// ---------------- vb [bs][kvh*64+d] -> vtb [b][kvh][d][s] ------------------
__global__ __launch_bounds__(256) void transpose_v(
    const ushort* __restrict__ vb, ushort* __restrict__ vtb)
{
  __shared__ ushort L[64][72];
  const int s0 = blockIdx.x * 64, kvh = blockIdx.y, b = blockIdx.z;
  const int t = threadIdx.x;
#pragma unroll
  for (int i = 0; i < 2; ++i) {
    const int cc = t + i * 256;
    const int srow = cc >> 3, c8 = (cc & 7) * 8;
    *(int4*)&L[srow][c8] =
        *(const int4*)(vb + ((size_t)(b * 2048 + s0 + srow)) * 256 + kvh * 64 + c8);
  }
  __syncthreads();
#pragma unroll
  for (int i = 0; i < 2; ++i) {
    const int cc = t + i * 256;
    const int drow = cc >> 3, s8 = (cc & 7) * 8;
    ushort w[8];
#pragma unroll
    for (int jj = 0; jj < 8; ++jj) w[jj] = L[s8 + jj][drow];
    *(int4*)(vtb + ((size_t)((b * 4 + kvh) * 64 + drow)) * 2048 + s0 + s8) =
        *(int4*)w;
  }
}

// ---------------- MFMA flash attention, fixed-max softmax ------------------
// p = exp2(s*0.125*log2e - 12*log2e), exact shift of softmax (bound 11.52).
// v4: T14 double-buffer, ONE barrier per tile (clean retest of the single
// defensible R1 component — no inline asm, no setprio). Per tile: issue
// global loads for kt+1 right after the barrier (latency hides under
// QK/softmax/PV of kt), ds_write to the OTHER buffer after compute, one
// __syncthreads. Staged data/barrier semantics otherwise identical to R9.
// vones register denominator (verified R8/R9). XCD swizzle: 1024 blocks.
__global__ __launch_bounds__(256) void attn_mfma(
    const ushort* __restrict__ qb, const ushort* __restrict__ kb,
    const ushort* __restrict__ vtb, ushort* __restrict__ yb,
    const int* __restrict__ wptr)
{
  __shared__ ushort Ks[2][64][72];
  __shared__ ushort Vt[2][64][72];
  __shared__ ushort Ps[64][72];
  const int lin = (blockIdx.z * 16 + blockIdx.y) * 32 + blockIdx.x;  // [0,1024)
  const int swz = (lin & 7) * 128 + (lin >> 3);                      // bijective
  const int x8 = swz >> 7, local = swz & 127;
  const int qt = local & 31;
  const int hb = x8 * 4 + (local >> 5);
  const int h = hb & 15, b = hb >> 4;
  const int kvh = h >> 2, q0 = qt * 64;
  const int t = threadIdx.x, lane = t & 63, wave = t >> 6;
  const int quad = lane >> 4, l16 = lane & 15;
  const int Wwin = *wptr;

  v8s qf0, qf1;
  {
    const ushort* qp = qb + ((size_t)(b * 2048 + q0 + wave * 16 + l16)) * 1024
                          + h * 64 + quad * 8;
    qf0 = *(const v8s*)qp;
    qf1 = *(const v8s*)(qp + 32);
  }

  // constant bf16 ones operand for the denominator MFMA
  v8s vones;
#pragma unroll
  for (int i = 0; i < 8; ++i) vones[i] = (short)0x3F80;

  v4f o[5];
#pragma unroll
  for (int d = 0; d < 5; ++d) o[d] = (v4f){0.f, 0.f, 0.f, 0.f};

  const int lo = q0 - Wwin + 1;
  const int kt0 = (lo > 0) ? (lo >> 6) : 0;
  const int kt1 = (q0 + 63) >> 6;   // == qt

  // staging addresses: thread t covers rows r8 and r8+32, 8 cols from c8t
  const int r8 = t >> 3, c8t = (t & 7) * 8;
  const ushort* kbase = kb + ((size_t)(b * 2048 + r8)) * 256 + kvh * 64 + c8t;
  const ushort* vbase = vtb + ((size_t)((b * 4 + kvh) * 64 + r8)) * 2048 + c8t;

  // prologue: stage tile kt0 into buffer 0
  int4 kr[2], vr[2];
#pragma unroll
  for (int i = 0; i < 2; ++i) {
    kr[i] = *(const int4*)(kbase + (size_t)(kt0 * 64 + i * 32) * 256);
    vr[i] = *(const int4*)(vbase + (size_t)(i * 32) * 2048 + kt0 * 64);
  }
#pragma unroll
  for (int i = 0; i < 2; ++i) {
    *(int4*)&Ks[0][r8 + i * 32][c8t] = kr[i];
    *(int4*)&Vt[0][r8 + i * 32][c8t] = vr[i];
  }
  __syncthreads();

  int pb = 0;
  for (int kt = kt0; kt <= kt1; ++kt) {
    const bool more = (kt < kt1);
    // T14 issue-early: next tile's global loads in flight under this tile's
    // compute (consumed by the ds_write after the compute phase).
    if (more) {
#pragma unroll
      for (int i = 0; i < 2; ++i) {
        kr[i] = *(const int4*)(kbase + (size_t)((kt + 1) * 64 + i * 32) * 256);
        vr[i] = *(const int4*)(vbase + (size_t)(i * 32) * 2048 + (kt + 1) * 64);
      }
    }

    const bool needs_mask = (kt * 64 + 63 > q0) || (kt * 64 < q0 + 64 - Wwin);

    {
      const int qrow = q0 + wave * 16 + l16;
      ushort* prow = &Ps[wave * 16 + l16][0];
#pragma unroll
      for (int nt = 0; nt < 4; ++nt) {
        v8s kf0 = *(const v8s*)&Ks[pb][nt * 16 + l16][quad * 8];
        v8s kf1 = *(const v8s*)&Ks[pb][nt * 16 + l16][32 + quad * 8];
        v4f st = (v4f){0.f, 0.f, 0.f, 0.f};
        st = __builtin_amdgcn_mfma_f32_16x16x32_bf16(kf0, qf0, st, 0, 0, 0);
        st = __builtin_amdgcn_mfma_f32_16x16x32_bf16(kf1, qf1, st, 0, 0, 0);
        float p[4];
#pragma unroll
        for (int r = 0; r < 4; ++r) {
          // 0.125*log2e, 12*log2e
          p[r] = exp2f(fmaf(st[r], 0.18033688011f, -17.31234049107f));
          if (needs_mask) {
            const int k = kt * 64 + nt * 16 + quad * 4 + r;
            const bool ok = (k <= qrow) && (k > qrow - Wwin);
            p[r] = ok ? p[r] : 0.0f;
          }
        }
        uint2 w;
        w.x = bpack(p[0], p[1]);
        w.y = bpack(p[2], p[3]);
        *(uint2*)(prow + nt * 16 + quad * 4) = w;
      }
    }

    v8s pf0 = *(const v8s*)&Ps[wave * 16 + l16][quad * 8];
    v8s pf1 = *(const v8s*)&Ps[wave * 16 + l16][32 + quad * 8];
#pragma unroll
    for (int dt = 0; dt < 4; ++dt) {
      v8s vf0 = *(const v8s*)&Vt[pb][dt * 16 + l16][quad * 8];
      v8s vf1 = *(const v8s*)&Vt[pb][dt * 16 + l16][32 + quad * 8];
      o[dt] = __builtin_amdgcn_mfma_f32_16x16x32_bf16(pf0, vf0, o[dt], 0, 0, 0);
      o[dt] = __builtin_amdgcn_mfma_f32_16x16x32_bf16(pf1, vf1, o[dt], 0, 0, 0);
    }
    o[4] = __builtin_amdgcn_mfma_f32_16x16x32_bf16(pf0, vones, o[4], 0, 0, 0);
    o[4] = __builtin_amdgcn_mfma_f32_16x16x32_bf16(pf1, vones, o[4], 0, 0, 0);

    // write-late: next tile to the other buffer; nobody reads it until after
    // the barrier, and this tile's buffer isn't written -> one barrier/tile.
    if (more) {
#pragma unroll
      for (int i = 0; i < 2; ++i) {
        *(int4*)&Ks[pb ^ 1][r8 + i * 32][c8t] = kr[i];
        *(int4*)&Vt[pb ^ 1][r8 + i * 32][c8t] = vr[i];
      }
      __syncthreads();
      pb ^= 1;
    }
  }

#pragma unroll
  for (int r = 0; r < 4; ++r) {
    const float l = __shfl(o[4][r], lane & 48);
    const float inv = 1.0f / l;
    ushort* yp = yb + ((size_t)(b * 2048 + q0 + wave * 16 + quad * 4 + r)) * 1024
                    + h * 64 + l16;
#pragma unroll
    for (int dt = 0; dt < 4; ++dt) yp[dt * 16] = b1(o[dt][r] * inv);
  }
}

// ---------------------------------------------------------------------------
extern "C" void kernel_launch(void* const* d_in, const int* in_sizes, int n_in,
                              void* d_out, int out_size, void* d_ws, size_t ws_size,
                              hipStream_t stream)
{
  const float* x    = (const float*)d_in[0];
  const float* ve   = (const float*)d_in[1];
  const float* cosp = (const float*)d_in[2];
  const float* sinp = (const float*)d_in[3];
  const float* Wq   = (const float*)d_in[4];
  const float* Wk   = (const float*)d_in[5];
  const float* Wv   = (const float*)d_in[6];
  const float* Wo   = (const float*)d_in[7];
  const float* Wg   = (const float*)d_in[8];
  const int*   win  = (const int*)d_in[9];
  float* out = (float*)d_out;

  char* p = (char*)d_ws;
  ushort* xb    = (ushort*)p;  p += (size_t)4194304 * 2;      //  8 MB
  ushort* qb    = (ushort*)p;  p += (size_t)4194304 * 2;      //  8 MB
  ushort* yb    = (ushort*)p;  p += (size_t)4194304 * 2;      //  8 MB
  ushort* kb    = (ushort*)p;  p += (size_t)1048576 * 2;      //  2 MB
  ushort* vb    = (ushort*)p;  p += (size_t)1048576 * 2;      //  2 MB
  ushort* vtb   = (ushort*)p;  p += (size_t)1048576 * 2;      //  2 MB
  ushort* Wqkvt = (ushort*)p;  p += (size_t)1536 * 1024 * 2;  //  3 MB
  ushort* Wot   = (ushort*)p;  p += (size_t)1048576 * 2;      //  2 MB
  float2* cs    = (float2*)p;  p += (size_t)65536 * 8;        // .5 MB
  float*  gates = (float*)p;                                  // 64 KB

  prep_all<<<6912, 256, 0, stream>>>(
      x, xb, Wg, gates, cosp, sinp, cs, Wq, Wk, Wv, Wo,
      Wqkvt, Wqkvt + (size_t)1024 * 1024, Wqkvt + (size_t)1280 * 1024, Wot);

  gemm_qkv_fused<<<dim3(64, 12), 256, 0, stream>>>(xb, Wqkvt, cs, gates, ve,
                                                   qb, kb, vb);
  transpose_v<<<dim3(32, 4, 2), 256, 0, stream>>>(vb, vtb);

  attn_mfma<<<dim3(32, 16, 2), 256, 0, stream>>>(qb, kb, vtb, yb, win);

  gemm_wo<<<dim3(128, 8), 256, 0, stream>>>(yb, Wot, out);
}

// Round 11
// 155.272 us; speedup vs baseline: 1.1966x; 1.1966x over previous
//
#include <hip/hip_runtime.h>
#include <hip/hip_bf16.h>
#include <cstddef>
#include <cstdint>

// B=2, S=2048, D=1024, H=16, KVH=4, hd=64. window from d_in[9].

typedef short v8s __attribute__((ext_vector_type(8)));
typedef float v4f __attribute__((ext_vector_type(4)));

// Exact RNE fp32->bf16 for FINITE values (no NaN path): 3 VALU ops.
__device__ __forceinline__ ushort b1(float a) {
  uint u = __float_as_uint(a);
  return (ushort)((u + 0x7FFFu + ((u >> 16) & 1u)) >> 16);
}
// Packed pair (lo, hi) -> one uint.
__device__ __forceinline__ uint bpack(float lo, float hi) {
  uint ul = __float_as_uint(lo), uh = __float_as_uint(hi);
  ul = (ul + 0x7FFFu + ((ul >> 16) & 1u)) >> 16;
  uh = (uh + 0x7FFFu + ((uh >> 16) & 1u)) & 0xFFFF0000u;
  return ul | uh;
}

// CK-style async global->LDS 16B/lane copy (wave-uniform LDS base + lane*16).
__device__ __forceinline__ void async16(const ushort* g, ushort* l) {
  __builtin_amdgcn_global_load_lds(
      (__attribute__((address_space(1))) void*)(uintptr_t)(const void*)g,
      (__attribute__((address_space(3))) void*)(uintptr_t)(void*)l, 16, 0, 0);
}

// ---------------- merged prep: x-cvt+gates | cs pack | 4 weight transposes --
// blocks 0..4095: x->bf16 + gates; 4096..4351: cs pack; 4352..6911: transposes.
__global__ __launch_bounds__(256) void prep_all(
    const float* __restrict__ x, ushort* __restrict__ xb,
    const float* __restrict__ Wg, float* __restrict__ gates,
    const float* __restrict__ cosp, const float* __restrict__ sinp,
    float2* __restrict__ cs,
    const float* __restrict__ Wq, const float* __restrict__ Wk,
    const float* __restrict__ Wv, const float* __restrict__ Wo,
    ushort* __restrict__ Wqt, ushort* __restrict__ Wkt,
    ushort* __restrict__ Wvt, ushort* __restrict__ Wot)
{
  const int bx = blockIdx.x, t = threadIdx.x;
  if (bx < 4096) {
    const float* row = x + (size_t)bx * 1024;
    float4 v = *(const float4*)(row + t * 4);
    ushort4 o;
    o.x = b1(v.x); o.y = b1(v.y); o.z = b1(v.z); o.w = b1(v.w);
    *(ushort4*)(xb + (size_t)bx * 1024 + t * 4) = o;
    if (t < 4) {
      float g = 0.f;
#pragma unroll
      for (int i = 0; i < 12; ++i) g += row[i] * Wg[i * 4 + t];
      gates[bx * 4 + t] = 3.0f / (1.0f + __expf(-g));
    }
    return;
  }
  if (bx < 4352) {
    const int i = (bx - 4096) * 256 + t;   // 65536 total
    cs[i] = make_float2(cosp[i], sinp[i]);
    return;
  }
  // transpose sections
  __shared__ ushort tile[32][33];
  int u = bx - 4352;
  const float* W; ushort* Wt; int N, xx, yy;
  if (u < 1024)      { W = Wq; Wt = Wqt; N = 1024; xx = u & 31; yy = u >> 5; }
  else if (u < 2048) { u -= 1024; W = Wo; Wt = Wot; N = 1024; xx = u & 31; yy = u >> 5; }
  else if (u < 2304) { u -= 2048; W = Wk; Wt = Wkt; N = 256;  xx = u & 7;  yy = u >> 3; }
  else               { u -= 2304; W = Wv; Wt = Wvt; N = 256;  xx = u & 7;  yy = u >> 3; }
  const int n0 = xx * 32, k0 = yy * 32;
  const int tx = t & 31, ty = t >> 5;
#pragma unroll
  for (int i = 0; i < 4; ++i) {
    const int k = ty + i * 8;
    tile[k][tx] = b1(W[(size_t)(k0 + k) * N + n0 + tx]);
  }
  __syncthreads();
#pragma unroll
  for (int i = 0; i < 4; ++i) {
    const int n = ty + i * 8;
    Wt[(size_t)(n0 + n) * 1024 + k0 + tx] = tile[tx][n];
  }
}

// ---------------- GEMM mainloop: 2-phase dbuf, 64x128, BK=64, T2 swizzle ---
//   store: lane loads global col ((lane&7)^(lane>>3))*8 -> linear dest
//   read : col = (ks*32+quad*8) ^ ((row&7)*8), row&7 == l16&7
__device__ __forceinline__ void gemm_mainloop(
    const ushort* __restrict__ A, const ushort* __restrict__ Bt,
    int K, int m0, int n0, ushort (*As)[64], ushort (*Bs)[64],
    v4f acc[2][4])
{
  const int t = threadIdx.x;
  const int lane = t & 63, wave = t >> 6;
  const int wr = wave >> 1, wc = wave & 1;
  const int quad = lane >> 4, l16 = lane & 15;
  const int l8 = lane >> 3;
  const int c8s = ((lane & 7) ^ l8) * 8;   // pre-swizzled global column
  const int sc = (l16 & 7) * 8;            // read-side XOR term

  const ushort* ap[2];
  ushort* al[2];
#pragma unroll
  for (int i = 0; i < 2; ++i) {
    const int row = wave * 8 + i * 32 + l8;   // row base multiple of 8
    ap[i] = A + (size_t)(m0 + row) * K + c8s;
    al[i] = &As[wave * 8 + i * 32][0];   // wave-uniform; HW adds lane*16B
  }
  const ushort* bp[4];
  ushort* bl[4];
#pragma unroll
  for (int i = 0; i < 4; ++i) {
    const int row = (wave * 4 + i) * 8 + l8;  // row base multiple of 8
    bp[i] = Bt + (size_t)(n0 + row) * K + c8s;
    bl[i] = &Bs[(wave * 4 + i) * 8][0];
  }

  auto stage = [&](int buf, int k0) {
#pragma unroll
    for (int i = 0; i < 2; ++i) async16(ap[i] + k0, al[i] + buf * (64 * 64));
#pragma unroll
    for (int i = 0; i < 4; ++i) async16(bp[i] + k0, bl[i] + buf * (128 * 64));
  };
  auto compute = [&](int buf) {
#pragma unroll
    for (int ks = 0; ks < 2; ++ks) {
      const int col = (ks * 32 + quad * 8) ^ sc;
      v8s af[2], bf[4];
#pragma unroll
      for (int i = 0; i < 2; ++i)
        af[i] = *(const v8s*)&As[buf * 64 + wr * 32 + i * 16 + l16][col];
#pragma unroll
      for (int i = 0; i < 4; ++i)
        bf[i] = *(const v8s*)&Bs[buf * 128 + wc * 64 + i * 16 + l16][col];
#pragma unroll
      for (int mt = 0; mt < 2; ++mt)
#pragma unroll
        for (int nt = 0; nt < 4; ++nt)
          acc[mt][nt] = __builtin_amdgcn_mfma_f32_16x16x32_bf16(
              af[mt], bf[nt], acc[mt][nt], 0, 0, 0);
    }
  };

  stage(0, 0);
  __syncthreads();
  int buf = 0;
  for (int k0 = 64; k0 < K; k0 += 64) {
    stage(buf ^ 1, k0);   // next tile in flight during compute
    compute(buf);
    __syncthreads();      // implicit vmcnt(0): prefetch done; buf reusable
    buf ^= 1;
  }
  compute(buf);           // last tile (no prefetch)
}

// ---------------- GEMM mainloop: 2-phase dbuf, 32x128 (gemm_wo), swizzled --
__device__ __forceinline__ void gemm_mainloop32(
    const ushort* __restrict__ A, const ushort* __restrict__ Bt,
    int K, int m0, int n0, ushort (*As)[64], ushort (*Bs)[64],
    v4f acc[4])
{
  const int t = threadIdx.x;
  const int lane = t & 63, wave = t >> 6;
  const int wr = wave >> 1, wc = wave & 1;
  const int quad = lane >> 4, l16 = lane & 15;
  const int l8 = lane >> 3;
  const int c8s = ((lane & 7) ^ l8) * 8;
  const int sc = (l16 & 7) * 8;

  const ushort* ap = A + (size_t)(m0 + wave * 8 + l8) * K + c8s;
  ushort* al = &As[wave * 8][0];
  const ushort* bp[4];
  ushort* bl[4];
#pragma unroll
  for (int i = 0; i < 4; ++i) {
    const int row = (wave * 4 + i) * 8 + l8;
    bp[i] = Bt + (size_t)(n0 + row) * K + c8s;
    bl[i] = &Bs[(wave * 4 + i) * 8][0];
  }

  auto stage = [&](int buf, int k0) {
    async16(ap + k0, al + buf * (32 * 64));
#pragma unroll
    for (int i = 0; i < 4; ++i) async16(bp[i] + k0, bl[i] + buf * (128 * 64));
  };
  auto compute = [&](int buf) {
#pragma unroll
    for (int ks = 0; ks < 2; ++ks) {
      const int col = (ks * 32 + quad * 8) ^ sc;
      v8s af = *(const v8s*)&As[buf * 32 + wr * 16 + l16][col];
      v8s bf[4];
#pragma unroll
      for (int i = 0; i < 4; ++i)
        bf[i] = *(const v8s*)&Bs[buf * 128 + wc * 64 + i * 16 + l16][col];
#pragma unroll
      for (int nt = 0; nt < 4; ++nt)
        acc[nt] = __builtin_amdgcn_mfma_f32_16x16x32_bf16(af, bf[nt], acc[nt], 0, 0, 0);
    }
  };

  stage(0, 0);
  __syncthreads();
  int buf = 0;
  for (int k0 = 64; k0 < K; k0 += 64) {
    stage(buf ^ 1, k0);
    compute(buf);
    __syncthreads();
    buf ^= 1;
  }
  compute(buf);
}

// ---------------- QKV GEMM with fused rope/rmsnorm/gate epilogue -----------
// XCD swizzle (T1): 768 blocks, 96/XCD.
__global__ __launch_bounds__(256) void gemm_qkv_fused(
    const ushort* __restrict__ A, const ushort* __restrict__ Bt,
    const float2* __restrict__ cs, const float* __restrict__ gates,
    const float* __restrict__ ve,
    ushort* __restrict__ qb, ushort* __restrict__ kb, ushort* __restrict__ vb)
{
  __shared__ ushort As[128][64];   // 2 x 64 rows (dbuf)
  __shared__ ushort Bs[256][64];   // 2 x 128 rows (dbuf)
  const int lin = blockIdx.y * 64 + blockIdx.x;        // [0,768)
  const int swz = (lin & 7) * 96 + (lin >> 3);         // bijective
  const int x8 = swz / 96, local = swz % 96;
  const int bxx = x8 * 8 + (local & 7), sec = local >> 3;
  const int m0 = bxx * 64, n0 = sec * 128;
  const int lane = threadIdx.x & 63, wave = threadIdx.x >> 6;
  const int wr = wave >> 1, wc = wave & 1;
  const int quad = lane >> 4, l16 = lane & 15;

  v4f acc[2][4];
#pragma unroll
  for (int i = 0; i < 2; ++i)
#pragma unroll
    for (int j = 0; j < 4; ++j) acc[i][j] = (v4f){0.f, 0.f, 0.f, 0.f};

  gemm_mainloop(A, Bt, 1024, m0, n0, As, Bs, acc);

  const int head_col = n0 + wc * 64;

  if (sec < 10) {
    const bool isQ = (sec < 8);
    const int h = (head_col - (isQ ? 0 : 1024)) >> 6;
    ushort* dst = isQ ? qb : kb;
    const int ld = isQ ? 1024 : 256;
#pragma unroll
    for (int mt = 0; mt < 2; ++mt)
#pragma unroll
      for (int r = 0; r < 4; ++r) {
        const int row = m0 + wr * 32 + mt * 16 + quad * 4 + r;
        const int s = row & 2047;
        const float2 cs0 = cs[s * 32 + l16];
        const float2 cs1 = cs[s * 32 + 16 + l16];
        const float x10 = acc[mt][0][r], x11 = acc[mt][1][r];
        const float x20 = acc[mt][2][r], x21 = acc[mt][3][r];
        float ss = x10 * x10 + x11 * x11 + x20 * x20 + x21 * x21;
        ss += __shfl_xor(ss, 1);
        ss += __shfl_xor(ss, 2);
        ss += __shfl_xor(ss, 4);
        ss += __shfl_xor(ss, 8);
        const float rs = rsqrtf(ss * (1.0f / 64.0f) + 1e-6f) * 1.2f;
        ushort* dp = dst + (size_t)row * ld + h * 64 + l16;
        dp[0]  = b1((x10 * cs0.x + x20 * cs0.y) * rs);
        dp[16] = b1((x11 * cs1.x + x21 * cs1.y) * rs);
        dp[32] = b1((-x10 * cs0.y + x20 * cs0.x) * rs);
        dp[48] = b1((-x11 * cs1.y + x21 * cs1.x) * rs);
      }
  } else {
    const int kvh = (head_col - 1280) >> 6;
#pragma unroll
    for (int mt = 0; mt < 2; ++mt)
#pragma unroll
      for (int r = 0; r < 4; ++r) {
        const int row = m0 + wr * 32 + mt * 16 + quad * 4 + r;
        const float gate = gates[row * 4 + kvh];
        const float* vep = ve + (size_t)row * 256 + kvh * 64 + l16;
        ushort* dp = vb + (size_t)row * 256 + kvh * 64 + l16;
#pragma unroll
        for (int nt = 0; nt < 4; ++nt)
          dp[nt * 16] = b1(acc[mt][nt][r] + gate * vep[nt * 16]);
      }
  }
}

// ---------------- Wo GEMM: 32x128 tile, plain fp32 epilogue ----------------
// XCD swizzle: 1024 blocks, 128/XCD.
__global__ __launch_bounds__(256) void gemm_wo(
    const ushort* __restrict__ A, const ushort* __restrict__ Bt,
    float* __restrict__ C)
{
  __shared__ ushort As[64][64];    // 2 x 32 rows (dbuf)
  __shared__ ushort Bs[256][64];   // 2 x 128 rows (dbuf)
  const int lin = blockIdx.y * 128 + blockIdx.x;       // [0,1024)
  const int swz = (lin & 7) * 128 + (lin >> 3);        // bijective
  const int x8 = swz >> 7, local = swz & 127;
  const int bxx = x8 * 16 + (local & 15), byy = local >> 4;
  const int m0 = bxx * 32, n0 = byy * 128;
  const int lane = threadIdx.x & 63, wave = threadIdx.x >> 6;
  const int wr = wave >> 1, wc = wave & 1;
  const int quad = lane >> 4, l16 = lane & 15;

  v4f acc[4];
#pragma unroll
  for (int j = 0; j < 4; ++j) acc[j] = (v4f){0.f, 0.f, 0.f, 0.f};

  gemm_mainloop32(A, Bt, 1024, m0, n0, As, Bs, acc);

#pragma unroll
  for (int r = 0; r < 4; ++r) {
    float* cp = C + (size_t)(m0 + wr * 16 + quad * 4 + r) * 1024
                  + n0 + wc * 64 + l16;
#pragma unroll
    for (int nt = 0; nt < 4; ++nt) cp[nt * 16] = acc[nt][r];
  }
}

// ---------------- vb [bs][kvh*64+d] -> vtb [b][kvh][d][s] ------------------
__global__ __launch_bounds__(256) void transpose_v(
    const ushort* __restrict__ vb, ushort* __restrict__ vtb)
{
  __shared__ ushort L[64][72];
  const int s0 = blockIdx.x * 64, kvh = blockIdx.y, b = blockIdx.z;
  const int t = threadIdx.x;
#pragma unroll
  for (int i = 0; i < 2; ++i) {
    const int cc = t + i * 256;
    const int srow = cc >> 3, c8 = (cc & 7) * 8;
    *(int4*)&L[srow][c8] =
        *(const int4*)(vb + ((size_t)(b * 2048 + s0 + srow)) * 256 + kvh * 64 + c8);
  }
  __syncthreads();
#pragma unroll
  for (int i = 0; i < 2; ++i) {
    const int cc = t + i * 256;
    const int drow = cc >> 3, s8 = (cc & 7) * 8;
    ushort w[8];
#pragma unroll
    for (int jj = 0; jj < 8; ++jj) w[jj] = L[s8 + jj][drow];
    *(int4*)(vtb + ((size_t)((b * 4 + kvh) * 64 + drow)) * 2048 + s0 + s8) =
        *(int4*)w;
  }
}

// ---------------- MFMA flash attention, fixed-max softmax ------------------
// p = exp2(s*0.125*log2e - 12*log2e), exact shift of softmax (bound 11.52).
// EXACT R7 structure (measured best, 155.8us total): single-buffer LDS-staged
// K/V, 2 barriers/tile, LDS ones-rows for the denominator, bpack, XCD
// swizzle. Both dbuf variants (R1: 74.5KB, R10: 54KB LDS) halved blocks/CU
// (occ 14-16%) and regressed 2x — this kernel's latency hiding is BLOCK-level
// parallelism (27.6KB -> 4-5 blocks/CU), so LDS growth is the dominant cost.
__global__ __launch_bounds__(256) void attn_mfma(
    const ushort* __restrict__ qb, const ushort* __restrict__ kb,
    const ushort* __restrict__ vtb, ushort* __restrict__ yb,
    const int* __restrict__ wptr)
{
  __shared__ ushort Ks[64][72];
  __shared__ ushort Vt[80][72];
  __shared__ ushort Ps[64][72];
  const int lin = (blockIdx.z * 16 + blockIdx.y) * 32 + blockIdx.x;  // [0,1024)
  const int swz = (lin & 7) * 128 + (lin >> 3);                      // bijective
  const int x8 = swz >> 7, local = swz & 127;
  const int qt = local & 31;
  const int hb = x8 * 4 + (local >> 5);
  const int h = hb & 15, b = hb >> 4;
  const int kvh = h >> 2, q0 = qt * 64;
  const int t = threadIdx.x, lane = t & 63, wave = t >> 6;
  const int quad = lane >> 4, l16 = lane & 15;
  const int Wwin = *wptr;

  v8s qf0, qf1;
  {
    const ushort* qp = qb + ((size_t)(b * 2048 + q0 + wave * 16 + l16)) * 1024
                          + h * 64 + quad * 8;
    qf0 = *(const v8s*)qp;
    qf1 = *(const v8s*)(qp + 32);
  }

  if (t < 128) {
    const int row = 64 + (t >> 3), c8 = (t & 7) * 8;
    const int v = (row == 64) ? 0x3F803F80 : 0;
    int4 w; w.x = v; w.y = v; w.z = v; w.w = v;
    *(int4*)&Vt[row][c8] = w;
  }

  v4f o[5];
#pragma unroll
  for (int d = 0; d < 5; ++d) o[d] = (v4f){0.f, 0.f, 0.f, 0.f};

  const int lo = q0 - Wwin + 1;
  const int kt0 = (lo > 0) ? (lo >> 6) : 0;
  const int kt1 = (q0 + 63) >> 6;   // == qt

  for (int kt = kt0; kt <= kt1; ++kt) {
#pragma unroll
    for (int i = 0; i < 2; ++i) {
      const int cc = t + i * 256;
      const int r8 = cc >> 3, c8 = (cc & 7) * 8;
      *(int4*)&Ks[r8][c8] =
          *(const int4*)(kb + ((size_t)(b * 2048 + kt * 64 + r8)) * 256 + kvh * 64 + c8);
      *(int4*)&Vt[r8][c8] =
          *(const int4*)(vtb + ((size_t)((b * 4 + kvh) * 64 + r8)) * 2048 + kt * 64 + c8);
    }
    __syncthreads();

    const bool needs_mask = (kt * 64 + 63 > q0) || (kt * 64 < q0 + 64 - Wwin);

    {
      const int qrow = q0 + wave * 16 + l16;
      ushort* prow = &Ps[wave * 16 + l16][0];
#pragma unroll
      for (int nt = 0; nt < 4; ++nt) {
        v8s kf0 = *(const v8s*)&Ks[nt * 16 + l16][quad * 8];
        v8s kf1 = *(const v8s*)&Ks[nt * 16 + l16][32 + quad * 8];
        v4f st = (v4f){0.f, 0.f, 0.f, 0.f};
        st = __builtin_amdgcn_mfma_f32_16x16x32_bf16(kf0, qf0, st, 0, 0, 0);
        st = __builtin_amdgcn_mfma_f32_16x16x32_bf16(kf1, qf1, st, 0, 0, 0);
        float p[4];
#pragma unroll
        for (int r = 0; r < 4; ++r) {
          // 0.125*log2e, 12*log2e
          p[r] = exp2f(fmaf(st[r], 0.18033688011f, -17.31234049107f));
          if (needs_mask) {
            const int k = kt * 64 + nt * 16 + quad * 4 + r;
            const bool ok = (k <= qrow) && (k > qrow - Wwin);
            p[r] = ok ? p[r] : 0.0f;
          }
        }
        uint2 w;
        w.x = bpack(p[0], p[1]);
        w.y = bpack(p[2], p[3]);
        *(uint2*)(prow + nt * 16 + quad * 4) = w;
      }
    }

    v8s pf0 = *(const v8s*)&Ps[wave * 16 + l16][quad * 8];
    v8s pf1 = *(const v8s*)&Ps[wave * 16 + l16][32 + quad * 8];
#pragma unroll
    for (int dt = 0; dt < 5; ++dt) {
      v8s vf0 = *(const v8s*)&Vt[dt * 16 + l16][quad * 8];
      v8s vf1 = *(const v8s*)&Vt[dt * 16 + l16][32 + quad * 8];
      o[dt] = __builtin_amdgcn_mfma_f32_16x16x32_bf16(pf0, vf0, o[dt], 0, 0, 0);
      o[dt] = __builtin_amdgcn_mfma_f32_16x16x32_bf16(pf1, vf1, o[dt], 0, 0, 0);
    }
    __syncthreads();
  }

#pragma unroll
  for (int r = 0; r < 4; ++r) {
    const float l = __shfl(o[4][r], lane & 48);
    const float inv = 1.0f / l;
    ushort* yp = yb + ((size_t)(b * 2048 + q0 + wave * 16 + quad * 4 + r)) * 1024
                    + h * 64 + l16;
#pragma unroll
    for (int dt = 0; dt < 4; ++dt) yp[dt * 16] = b1(o[dt][r] * inv);
  }
}

// ---------------------------------------------------------------------------
extern "C" void kernel_launch(void* const* d_in, const int* in_sizes, int n_in,
                              void* d_out, int out_size, void* d_ws, size_t ws_size,
                              hipStream_t stream)
{
  const float* x    = (const float*)d_in[0];
  const float* ve   = (const float*)d_in[1];
  const float* cosp = (const float*)d_in[2];
  const float* sinp = (const float*)d_in[3];
  const float* Wq   = (const float*)d_in[4];
  const float* Wk   = (const float*)d_in[5];
  const float* Wv   = (const float*)d_in[6];
  const float* Wo   = (const float*)d_in[7];
  const float* Wg   = (const float*)d_in[8];
  const int*   win  = (const int*)d_in[9];
  float* out = (float*)d_out;

  char* p = (char*)d_ws;
  ushort* xb    = (ushort*)p;  p += (size_t)4194304 * 2;      //  8 MB
  ushort* qb    = (ushort*)p;  p += (size_t)4194304 * 2;      //  8 MB
  ushort* yb    = (ushort*)p;  p += (size_t)4194304 * 2;      //  8 MB
  ushort* kb    = (ushort*)p;  p += (size_t)1048576 * 2;      //  2 MB
  ushort* vb    = (ushort*)p;  p += (size_t)1048576 * 2;      //  2 MB
  ushort* vtb   = (ushort*)p;  p += (size_t)1048576 * 2;      //  2 MB
  ushort* Wqkvt = (ushort*)p;  p += (size_t)1536 * 1024 * 2;  //  3 MB
  ushort* Wot   = (ushort*)p;  p += (size_t)1048576 * 2;      //  2 MB
  float2* cs    = (float2*)p;  p += (size_t)65536 * 8;        // .5 MB
  float*  gates = (float*)p;                                  // 64 KB

  prep_all<<<6912, 256, 0, stream>>>(
      x, xb, Wg, gates, cosp, sinp, cs, Wq, Wk, Wv, Wo,
      Wqkvt, Wqkvt + (size_t)1024 * 1024, Wqkvt + (size_t)1280 * 1024, Wot);

  gemm_qkv_fused<<<dim3(64, 12), 256, 0, stream>>>(xb, Wqkvt, cs, gates, ve,
                                                   qb, kb, vb);
  transpose_v<<<dim3(32, 4, 2), 256, 0, stream>>>(vb, vtb);

  attn_mfma<<<dim3(32, 16, 2), 256, 0, stream>>>(qb, kb, vtb, yb, win);

  gemm_wo<<<dim3(128, 8), 256, 0, stream>>>(yb, Wot, out);
}